// Round 2
// baseline (609.262 us; speedup 1.0000x reference)
//
#include <hip/hip_runtime.h>

// VQ: latent [32768,8,32] f32, codebook [128,32] f32.
// Outputs (concat in d_out, fp32):
//   policy_vq_latent [262144*32], quantized [262144*32], codebook_set [32768*128*32]
//
// Correctness strategy: bit-replicate the numpy reference's distance arithmetic
// so argmin matches on every row (one flip = ~1e-2 error >> 1.56e-4 threshold).
//   S = sum(x^2), c2 = sum(c^2): numpy pairwise-8 order for n=32
//   dot = (2x) @ cb.T: HYPOTHESIS (b) — sequential-k mul+add chain, NO FMA
//     (numpy no-BLAS matmul fallback / SSE-era OpenBLAS kernel; round 1's
//      FMA-chain hypothesis (a) was eliminated: bit-exact would give absmax 0,
//      we saw 1.12e-2 = ~1 flipped row)
//   dist = fl(fl(S + c2_k) - dot_k), strict < argmin (first-index ties)
//   policy = fl(x + fl(q - x))
// fp contract(off) stops hipcc re-fusing mul+add into FMA.

typedef float f32x4 __attribute__((ext_vector_type(4)));

constexpr int N_ROWS    = 32768 * 8;   // 262144 flat vectors
constexpr int KCODES    = 128;
constexpr int DIM       = 32;
constexpr int THREADS   = 256;
constexpr int VQ_BLOCKS = N_ROWS / THREADS;  // 1024 (1 row per thread)
constexpr int BC_BLOCKS = 2048;              // broadcast blocks
constexpr long long QUANT_OFF = (long long)N_ROWS * DIM;   //  8388608 floats
constexpr long long CBSET_OFF = 2LL * N_ROWS * DIM;        // 16777216 floats
constexpr int CBSET_F4 = (int)(32768LL * 128 * 32 / 4);    // 33554432 float4
constexpr int PERIOD_F4_MASK = 1023;  // 4096 floats per codebook copy = 1024 f4

__global__ __launch_bounds__(THREADS)
void vq_fused_kernel(const float* __restrict__ latent,
                     const float* __restrict__ codebook,
                     float* __restrict__ out) {
#pragma clang fp contract(off)
    __shared__ float s_cb[KCODES * DIM];  // 16 KB
    __shared__ float s_c2[KCODES];

    const int tid = threadIdx.x;
    const int bid = blockIdx.x;

    if (bid < VQ_BLOCKS) {
        // ---- stage codebook to LDS (coalesced float4) ----
        {
            f32x4* s4 = (f32x4*)s_cb;
            const f32x4* g4 = (const f32x4*)codebook;
            #pragma unroll
            for (int j = 0; j < (KCODES * DIM / 4) / THREADS; ++j)  // 4 iters
                s4[tid + THREADS * j] = g4[tid + THREADS * j];
        }
        __syncthreads();

        // ---- c2[k] = sum(c_k^2) in numpy pairwise-8 order ----
        if (tid < KCODES) {
            const float* c = &s_cb[tid * DIM];
            float t[DIM];
            #pragma unroll
            for (int d = 0; d < DIM; ++d) t[d] = c[d] * c[d];
            float r[8];
            #pragma unroll
            for (int j = 0; j < 8; ++j)
                r[j] = ((t[j] + t[j + 8]) + t[j + 16]) + t[j + 24];
            s_c2[tid] = ((r[0] + r[1]) + (r[2] + r[3])) + ((r[4] + r[5]) + (r[6] + r[7]));
        }
        __syncthreads();

        // ---- per-row VQ ----
        const int row = bid * THREADS + tid;
        const f32x4* x4 = (const f32x4*)latent + (size_t)row * 8;

        float x2[DIM];  // 2*x (exact); x recovered later as 0.5*x2 (exact)
        float S;
        {
            float t[DIM];
            #pragma unroll
            for (int j = 0; j < 8; ++j) {
                f32x4 v = x4[j];
                #pragma unroll
                for (int e = 0; e < 4; ++e) {
                    float xv = v[e];
                    t[4 * j + e]  = xv * xv;     // individually rounded square
                    x2[4 * j + e] = 2.0f * xv;   // exact
                }
            }
            float r[8];
            #pragma unroll
            for (int j = 0; j < 8; ++j)
                r[j] = ((t[j] + t[j + 8]) + t[j + 16]) + t[j + 24];
            S = ((r[0] + r[1]) + (r[2] + r[3])) + ((r[4] + r[5]) + (r[6] + r[7]));
        }

        float best = 3.402823466e38f;
        int bestk = 0;
        const f32x4* c4 = (const f32x4*)s_cb;
        #pragma unroll 4
        for (int k = 0; k < KCODES; ++k) {
            // HYPOTHESIS (b): sequential mul+add chain (two roundings/term),
            // k-element order ascending, single accumulator starting at 0.
            float acc = 0.0f;
            #pragma unroll
            for (int j = 0; j < 8; ++j) {
                f32x4 cv = c4[k * 8 + j];  // uniform addr -> LDS broadcast
                #pragma unroll
                for (int e = 0; e < 4; ++e) {
                    float prod = x2[4 * j + e] * cv[e];  // fl(2x * c)
                    acc = acc + prod;                    // fl(acc + prod)
                }
            }
            float dist = (S + s_c2[k]) - acc;  // fl(fl(S+c2) - dot2)
            if (dist < best) { best = dist; bestk = k; }  // strict <: first min
        }

        // ---- epilogue: policy = x + (q - x), quantized = q ----
        f32x4* pol = (f32x4*)out + (size_t)row * 8;
        f32x4* qnt = (f32x4*)(out + QUANT_OFF) + (size_t)row * 8;
        const f32x4* q4 = (const f32x4*)&s_cb[bestk * DIM];
        #pragma unroll
        for (int j = 0; j < 8; ++j) {
            f32x4 q = q4[j];
            f32x4 p;
            #pragma unroll
            for (int e = 0; e < 4; ++e) {
                float xv = 0.5f * x2[4 * j + e];  // exact recovery of x
                p[e] = xv + (q[e] - xv);          // mirrors l + (q - l)
            }
            pol[j] = p;
            qnt[j] = q;
        }
    } else {
        // ---- broadcast codebook_set: out[b,k,d] = cb[k,d], 512 MiB stream ----
        const int btid = (bid - VQ_BLOCKS) * THREADS + tid;
        const int stride = BC_BLOCKS * THREADS;  // 524288 -> exactly 64 iters
        const f32x4* g4 = (const f32x4*)codebook;
        f32x4* o4 = (f32x4*)(out + CBSET_OFF);
        for (int i = btid; i < CBSET_F4; i += stride) {
            f32x4 v = g4[i & PERIOD_F4_MASK];  // L1-resident 16 KB table
            __builtin_nontemporal_store(v, &o4[i]);
        }
    }
}

extern "C" void kernel_launch(void* const* d_in, const int* in_sizes, int n_in,
                              void* d_out, int out_size, void* d_ws, size_t ws_size,
                              hipStream_t stream) {
    const float* latent   = (const float*)d_in[0];
    const float* codebook = (const float*)d_in[1];
    float* out = (float*)d_out;
    vq_fused_kernel<<<dim3(VQ_BLOCKS + BC_BLOCKS), dim3(THREADS), 0, stream>>>(
        latent, codebook, out);
}